// Round 3
// baseline (345.390 us; speedup 1.0000x reference)
//
#include <hip/hip_runtime.h>
#include <stdint.h>

// T-structure as a signed permutation: for each (k,p) there is exactly one q
// with sign s such that T[k,p,q] = s. Transcribed from _TERMS.
__constant__ signed char QTAB[64] = {
    0,1,2,3,4,5,6,7,
    1,0,4,5,2,3,7,6,
    2,4,0,6,1,7,3,5,
    3,5,6,0,7,1,2,4,
    4,2,1,7,0,6,5,3,
    5,3,7,1,6,0,4,2,
    6,7,3,2,5,4,0,1,
    7,6,5,4,3,2,1,0};
__constant__ signed char SGN[64] = {
    1, 1, 1, 1,-1,-1,-1,-1,
    1, 1,-1, 1, 1,-1,-1,-1,
    1, 1, 1,-1,-1, 1, 1,-1,
    1,-1, 1, 1,-1,-1,-1, 1,
    1, 1,-1, 1, 1,-1, 1,-1,
    1,-1, 1, 1, 1, 1,-1,-1,
    1,-1,-1, 1,-1, 1, 1, 1,
    1, 1,-1, 1, 1,-1, 1, 1};

// W2[iq][m] such that out[b][m] = sum_iq x[b][iq] * W2[iq][m]  (m = o*8+k,
// iq = i*8+q). Each entry written exactly once (QTAB rows are permutations).
__global__ void clifford_prep(const float* __restrict__ weight,
                              float* __restrict__ W2) {
    int t = threadIdx.x;
    for (int e = t; e < 4096; e += 256) {
        int o = e >> 9, i = (e >> 6) & 7, k = (e >> 3) & 7, p = e & 7;
        int q = (int)QTAB[k * 8 + p];
        float s = (float)SGN[k * 8 + p];
        W2[((i * 8 + q) * 64) + (o * 8 + k)] = s * weight[(o * 8 + i) * 8 + p];
    }
}

#define LSTR 33     // LDS row stride in floats (odd -> 2-way banks = free)
#define NBLK 1024   // persistent blocks: 4096 waves, 8 tiles/wave at nB=2^21

// One wave = one 64-batch tile per iteration, persistent grid-stride with
// cross-tile prefetch. Global traffic in 128-B contiguous segments; LDS
// (wave-private, no barriers) does the row<->lane transpose. Weights are
// wave-uniform -> scalar loads feeding v_fmac SGPR operands.
__global__ __launch_bounds__(256, 4) void clifford_main(
    const float* __restrict__ x, const float* __restrict__ W,
    const float* __restrict__ bias, float* __restrict__ out, int nB) {
    __shared__ float lds[4][64 * LSTR];
    const int wave = threadIdx.x >> 6;
    const int lane = threadIdx.x & 63;
    float* Lw = lds[wave];
    const int nT = nB >> 6;
    const int totw = NBLK * 4;
    const int r8 = lane >> 3;       // row-group member (8 rows apart)
    const int c8 = (lane & 7) * 4;  // column quad within a 32-col half

    int t = blockIdx.x * 4 + wave;
    if (t >= nT) return;

    float4 r0[8], r1[8];
    // ---- prologue: load half 0 of first tile ----
    {
        const float* xt = x + (long long)t * 64 * 64;
#pragma unroll
        for (int i = 0; i < 8; ++i)
            r0[i] = *(const float4*)(xt + (size_t)(r8 + 8 * i) * 64 + c8);
    }

    for (; t < nT; t += totw) {
        const float* xt = x + (long long)t * 64 * 64;
        float* ot = out + (long long)t * 64 * 64;

        // ---- stage half 0 ----
#pragma unroll
        for (int i = 0; i < 8; ++i) {
            int b = r8 + 8 * i;
            Lw[b * LSTR + c8 + 0] = r0[i].x;
            Lw[b * LSTR + c8 + 1] = r0[i].y;
            Lw[b * LSTR + c8 + 2] = r0[i].z;
            Lw[b * LSTR + c8 + 3] = r0[i].w;
        }

        // ---- issue load of half 1 (in flight during compute half 0) ----
#pragma unroll
        for (int i = 0; i < 8; ++i)
            r1[i] = *(const float4*)(xt + (size_t)(r8 + 8 * i) * 64 + 32 + c8);

        float acc[64];
#pragma unroll
        for (int m = 0; m < 64; ++m) acc[m] = bias[m];

        // ---- compute half 0 ----
#pragma unroll 2
        for (int iq = 0; iq < 32; ++iq) {
            float xv = Lw[lane * LSTR + iq];
            const float* Wr = W + iq * 64;  // wave-uniform -> s_load
#pragma unroll
            for (int m = 0; m < 64; ++m) acc[m] = fmaf(Wr[m], xv, acc[m]);
        }

        // ---- stage half 1 ----
#pragma unroll
        for (int i = 0; i < 8; ++i) {
            int b = r8 + 8 * i;
            Lw[b * LSTR + c8 + 0] = r1[i].x;
            Lw[b * LSTR + c8 + 1] = r1[i].y;
            Lw[b * LSTR + c8 + 2] = r1[i].z;
            Lw[b * LSTR + c8 + 3] = r1[i].w;
        }

        // ---- prefetch next tile's half 0 (wave-uniform branch) ----
        int tn = t + totw;
        if (tn < nT) {
            const float* xn = x + (long long)tn * 64 * 64;
#pragma unroll
            for (int i = 0; i < 8; ++i)
                r0[i] = *(const float4*)(xn + (size_t)(r8 + 8 * i) * 64 + c8);
        }

        // ---- compute half 1 ----
#pragma unroll 2
        for (int iq = 0; iq < 32; ++iq) {
            float xv = Lw[lane * LSTR + iq];
            const float* Wr = W + (32 + iq) * 64;
#pragma unroll
            for (int m = 0; m < 64; ++m) acc[m] = fmaf(Wr[m], xv, acc[m]);
        }

        // ---- store: transpose through LDS in two 32-col halves ----
#pragma unroll
        for (int mh = 0; mh < 2; ++mh) {
#pragma unroll
            for (int m = 0; m < 32; ++m)
                Lw[lane * LSTR + m] = acc[mh * 32 + m];
#pragma unroll
            for (int i = 0; i < 8; ++i) {
                int b = r8 + 8 * i;
                float4 v;
                v.x = Lw[b * LSTR + c8 + 0];
                v.y = Lw[b * LSTR + c8 + 1];
                v.z = Lw[b * LSTR + c8 + 2];
                v.w = Lw[b * LSTR + c8 + 3];
                *(float4*)(ot + (size_t)b * 64 + mh * 32 + c8) = v;
            }
        }
    }
}

extern "C" void kernel_launch(void* const* d_in, const int* in_sizes, int n_in,
                              void* d_out, int out_size, void* d_ws,
                              size_t ws_size, hipStream_t stream) {
    const float* x = (const float*)d_in[0];
    const float* weight = (const float*)d_in[1];
    const float* bias = (const float*)d_in[2];
    float* out = (float*)d_out;
    float* W2 = (float*)d_ws;  // 4096 floats = 16 KB scratch

    int nB = in_sizes[0] / 64;  // 4096*512 batch elements

    hipLaunchKernelGGL(clifford_prep, dim3(1), dim3(256), 0, stream, weight,
                       W2);
    int nTiles = (nB + 63) / 64;
    int blocks = NBLK;
    if (blocks * 4 > nTiles) blocks = (nTiles + 3) / 4;  // tiny-input guard
    hipLaunchKernelGGL(clifford_main, dim3(blocks), dim3(256), 0, stream, x,
                       W2, bias, out, nB);
}

// Round 4
// 252.447 us; speedup vs baseline: 1.3682x; 1.3682x over previous
//
#include <hip/hip_runtime.h>
#include <stdint.h>

// T-structure as a signed permutation: for each (k,p) there is exactly one q
// with sign s such that T[k,p,q] = s. Transcribed from _TERMS.
__constant__ signed char QTAB[64] = {
    0,1,2,3,4,5,6,7,
    1,0,4,5,2,3,7,6,
    2,4,0,6,1,7,3,5,
    3,5,6,0,7,1,2,4,
    4,2,1,7,0,6,5,3,
    5,3,7,1,6,0,4,2,
    6,7,3,2,5,4,0,1,
    7,6,5,4,3,2,1,0};
__constant__ signed char SGN[64] = {
    1, 1, 1, 1,-1,-1,-1,-1,
    1, 1,-1, 1, 1,-1,-1,-1,
    1, 1, 1,-1,-1, 1, 1,-1,
    1,-1, 1, 1,-1,-1,-1, 1,
    1, 1,-1, 1, 1,-1, 1,-1,
    1,-1, 1, 1, 1, 1,-1,-1,
    1,-1,-1, 1,-1, 1, 1, 1,
    1, 1,-1, 1, 1,-1, 1, 1};

// W2[iq][m] such that out[b][m] = sum_iq x[b][iq] * W2[iq][m]  (m = o*8+k,
// iq = i*8+q). Each entry written exactly once (QTAB rows are permutations).
__global__ void clifford_prep(const float* __restrict__ weight,
                              float* __restrict__ W2) {
    int t = threadIdx.x;
    for (int e = t; e < 4096; e += 256) {
        int o = e >> 9, i = (e >> 6) & 7, k = (e >> 3) & 7, p = e & 7;
        int q = (int)QTAB[k * 8 + p];
        float s = (float)SGN[k * 8 + p];
        W2[((i * 8 + q) * 64) + (o * 8 + k)] = s * weight[(o * 8 + i) * 8 + p];
    }
}

#define LSTR 33     // LDS row stride in floats (odd -> 2-way banks = free)
#define NBLK 1024   // persistent blocks: 4096 waves, 8 tiles/wave at nB=2^21

// One wave = one 64-batch tile per loop iteration, persistent grid-stride.
// NO cross-tile register prefetch and NO min-waves launch bound: R2 showed
// that combo forces acc[64] to spill (VGPR_Count=64, scratch traffic).
// Within a tile: both column-halves' global loads issue before any LDS
// stage (16 loads in flight), then stage/compute half0 while half1 is still
// inbound. Weights are wave-uniform -> scalar loads feeding v_fmac.
__global__ __launch_bounds__(256) void clifford_main(
    const float* __restrict__ x, const float* __restrict__ W,
    const float* __restrict__ bias, float* __restrict__ out, int nB) {
    __shared__ float lds[4][64 * LSTR];
    const int wave = threadIdx.x >> 6;
    const int lane = threadIdx.x & 63;
    float* Lw = lds[wave];
    const int nT = nB >> 6;
    const int totw = NBLK * 4;
    const int r8 = lane >> 3;       // row-group member (8 rows apart)
    const int c8 = (lane & 7) * 4;  // column quad within a 32-col half

    for (int t = blockIdx.x * 4 + wave; t < nT; t += totw) {
        const float* xt = x + (long long)t * 64 * 64;
        float* ot = out + (long long)t * 64 * 64;

        // ---- issue ALL 16 tile loads (2 halves) before any dependent use --
        float4 r0[8], r1[8];
#pragma unroll
        for (int i = 0; i < 8; ++i)
            r0[i] = *(const float4*)(xt + (size_t)(r8 + 8 * i) * 64 + c8);
#pragma unroll
        for (int i = 0; i < 8; ++i)
            r1[i] = *(const float4*)(xt + (size_t)(r8 + 8 * i) * 64 + 32 + c8);

        // ---- stage half 0 ----
#pragma unroll
        for (int i = 0; i < 8; ++i) {
            int b = r8 + 8 * i;
            Lw[b * LSTR + c8 + 0] = r0[i].x;
            Lw[b * LSTR + c8 + 1] = r0[i].y;
            Lw[b * LSTR + c8 + 2] = r0[i].z;
            Lw[b * LSTR + c8 + 3] = r0[i].w;
        }

        float acc[64];
#pragma unroll
        for (int m = 0; m < 64; ++m) acc[m] = bias[m];

        // ---- compute half 0 (half 1 loads still in flight) ----
#pragma unroll 2
        for (int iq = 0; iq < 32; ++iq) {
            float xv = Lw[lane * LSTR + iq];
            const float* Wr = W + iq * 64;  // wave-uniform -> s_load
#pragma unroll
            for (int m = 0; m < 64; ++m) acc[m] = fmaf(Wr[m], xv, acc[m]);
        }

        // ---- stage half 1 ----
#pragma unroll
        for (int i = 0; i < 8; ++i) {
            int b = r8 + 8 * i;
            Lw[b * LSTR + c8 + 0] = r1[i].x;
            Lw[b * LSTR + c8 + 1] = r1[i].y;
            Lw[b * LSTR + c8 + 2] = r1[i].z;
            Lw[b * LSTR + c8 + 3] = r1[i].w;
        }

        // ---- compute half 1 ----
#pragma unroll 2
        for (int iq = 0; iq < 32; ++iq) {
            float xv = Lw[lane * LSTR + iq];
            const float* Wr = W + (32 + iq) * 64;
#pragma unroll
            for (int m = 0; m < 64; ++m) acc[m] = fmaf(Wr[m], xv, acc[m]);
        }

        // ---- store: transpose through LDS in two 32-col halves ----
#pragma unroll
        for (int mh = 0; mh < 2; ++mh) {
#pragma unroll
            for (int m = 0; m < 32; ++m)
                Lw[lane * LSTR + m] = acc[mh * 32 + m];
#pragma unroll
            for (int i = 0; i < 8; ++i) {
                int b = r8 + 8 * i;
                float4 v;
                v.x = Lw[b * LSTR + c8 + 0];
                v.y = Lw[b * LSTR + c8 + 1];
                v.z = Lw[b * LSTR + c8 + 2];
                v.w = Lw[b * LSTR + c8 + 3];
                *(float4*)(ot + (size_t)b * 64 + mh * 32 + c8) = v;
            }
        }
    }
}

extern "C" void kernel_launch(void* const* d_in, const int* in_sizes, int n_in,
                              void* d_out, int out_size, void* d_ws,
                              size_t ws_size, hipStream_t stream) {
    const float* x = (const float*)d_in[0];
    const float* weight = (const float*)d_in[1];
    const float* bias = (const float*)d_in[2];
    float* out = (float*)d_out;
    float* W2 = (float*)d_ws;  // 4096 floats = 16 KB scratch

    int nB = in_sizes[0] / 64;  // 4096*512 batch elements

    hipLaunchKernelGGL(clifford_prep, dim3(1), dim3(256), 0, stream, weight,
                       W2);
    int nTiles = (nB + 63) / 64;
    int blocks = NBLK;
    if (blocks * 4 > nTiles) blocks = (nTiles + 3) / 4;  // tiny-input guard
    hipLaunchKernelGGL(clifford_main, dim3(blocks), dim3(256), 0, stream, x,
                       W2, bias, out, nB);
}